// Round 11
// baseline (931.270 us; speedup 1.0000x reference)
//
#include <hip/hip_runtime.h>

typedef unsigned short u16;
typedef float f32x4 __attribute__((ext_vector_type(4)));
typedef __bf16 bf16x8 __attribute__((ext_vector_type(8)));

#define AS1 __attribute__((address_space(1)))
#define AS3 __attribute__((address_space(3)))

__device__ __forceinline__ float bf2f(u16 h) {
  return __uint_as_float(((unsigned)h) << 16);
}
__device__ __forceinline__ u16 f2bf(float f) {
  unsigned u = __float_as_uint(f);
  unsigned r = (u + 0x7FFFu + ((u >> 16) & 1u)) >> 16;
  return (u16)r;
}
__device__ __forceinline__ void gload16(const u16* g, u16* l) {
  __builtin_amdgcn_global_load_lds((const AS1 void*)g, (AS3 void*)l, 16, 0, 0);
}

// ---------------------------------------------------------------- transpose
// out[C,R] = bf16(in[R,C]^T), in fp32; R,C multiples of 32
__global__ void transpose_k(const float* __restrict__ in, u16* __restrict__ out,
                            int R, int C) {
  __shared__ u16 t[32][33];
  int c0 = blockIdx.x * 32, r0 = blockIdx.y * 32;
  int tx = threadIdx.x & 31, ty = threadIdx.x >> 5; // 32 x 8
  for (int i = 0; i < 32; i += 8)
    t[ty + i][tx] = f2bf(in[(size_t)(r0 + ty + i) * C + c0 + tx]);
  __syncthreads();
  for (int i = 0; i < 32; i += 8)
    out[(size_t)(c0 + ty + i) * R + r0 + tx] = t[tx][ty + i];
}

// four 768x768 weight transposes in one launch (z selects)
__global__ void transpose4_k(const float* __restrict__ s0, const float* __restrict__ s1,
                             const float* __restrict__ s2, const float* __restrict__ s3,
                             u16* __restrict__ d0, u16* __restrict__ d1,
                             u16* __restrict__ d2, u16* __restrict__ d3) {
  __shared__ u16 t[32][33];
  const float* in = (blockIdx.z == 0) ? s0 : (blockIdx.z == 1) ? s1
                    : (blockIdx.z == 2) ? s2 : s3;
  u16* out = (blockIdx.z == 0) ? d0 : (blockIdx.z == 1) ? d1
             : (blockIdx.z == 2) ? d2 : d3;
  int c0 = blockIdx.x * 32, r0 = blockIdx.y * 32;
  int tx = threadIdx.x & 31, ty = threadIdx.x >> 5;
  for (int i = 0; i < 32; i += 8)
    t[ty + i][tx] = f2bf(in[(size_t)(r0 + ty + i) * 768 + c0 + tx]);
  __syncthreads();
  for (int i = 0; i < 32; i += 8)
    out[(size_t)(c0 + ty + i) * 768 + r0 + tx] = t[tx][ty + i];
}

// pack bq|bk|bv -> bqkv[2304] fp32
__global__ void pack3_k(const float* __restrict__ a, const float* __restrict__ b,
                        const float* __restrict__ c, float* __restrict__ out) {
  int i = blockIdx.x * 256 + threadIdx.x;
  float v = (i < 768) ? a[i] : (i < 1536) ? b[i - 768] : c[i - 1536];
  out[i] = v;
}

// V(bf16) [16,1024, h*96+d] (compact [16384,768]) -> VT [bh][96][1024]
__global__ void vtrans_k(const u16* __restrict__ v, u16* __restrict__ vt) {
  __shared__ u16 t[32][33];
  int bh = blockIdx.z, b = bh >> 3, h = bh & 7;
  int n0 = blockIdx.y * 32, d0 = blockIdx.x * 32;
  int tx = threadIdx.x & 31, ty = threadIdx.x >> 5;
  const u16* src = v + (size_t)(b * 1024) * 768 + h * 96;
  for (int i = 0; i < 32; i += 8)
    t[ty + i][tx] = src[(size_t)(n0 + ty + i) * 768 + d0 + tx];
  __syncthreads();
  u16* dst = vt + ((size_t)bh * 96 + d0) * 1024 + n0;
  for (int i = 0; i < 32; i += 8)
    dst[(size_t)(ty + i) * 1024 + tx] = t[tx][ty + i];
}

// ---------------------------------------------------------------- layernorm
__global__ __launch_bounds__(256) void ln_f32_k(const float* __restrict__ x,
                                                const float* __restrict__ gamma,
                                                const float* __restrict__ beta,
                                                u16* __restrict__ out) {
  __shared__ float red[8];
  int row = blockIdx.x, t = threadIdx.x;
  const float* xr = x + (size_t)row * 768;
  float v[3], s = 0.f, s2 = 0.f;
#pragma unroll
  for (int i = 0; i < 3; i++) {
    v[i] = xr[t + i * 256];
    s += v[i]; s2 += v[i] * v[i];
  }
#pragma unroll
  for (int off = 1; off < 64; off <<= 1) {
    s += __shfl_xor(s, off, 64);
    s2 += __shfl_xor(s2, off, 64);
  }
  int w = t >> 6;
  if ((t & 63) == 0) { red[w] = s; red[4 + w] = s2; }
  __syncthreads();
  s = red[0] + red[1] + red[2] + red[3];
  s2 = red[4] + red[5] + red[6] + red[7];
  float mu = s * (1.f / 768.f);
  float var = s2 * (1.f / 768.f) - mu * mu;
  float rs = rsqrtf(var + 1e-5f);
  u16* orow = out + (size_t)row * 768;
#pragma unroll
  for (int i = 0; i < 3; i++) {
    int c = t + i * 256;
    orow[c] = f2bf((v[i] - mu) * rs * gamma[c] + beta[c]);
  }
}

// ---------------------------------------------------------------- GEMM 128x128
// (kept for FFN2, K=3072 long-K case — R10-proven)
// Single 32KB buffer -> 5 blocks/CU; fragment-major 1KB subtiles (0
// conflicts); XCD swizzle.
#define BM 128
#define BN 128
#define BK 64

template <int EPI>
__global__ __launch_bounds__(256, 4) void gemm_bt(
    const u16* __restrict__ A, const u16* __restrict__ Bt,
    const float* __restrict__ bias, const float* __restrict__ res,
    void* __restrict__ Cv, int M, int N, int K, int lda) {
  __shared__ u16 As[BM * BK];
  __shared__ u16 Bs[BN * BK];
  int tid = threadIdx.x, lane = tid & 63, w = tid >> 6;
  int l15 = lane & 15, quad = lane >> 4;
  int wm = (w >> 1) * 64, wn = (w & 1) * 64;
  int GX = gridDim.x;
  int f = blockIdx.y * GX + blockIdx.x;
  int mpx = GX >> 3;
  int xcd = f & 7, idx = f >> 3;
  int m0 = (xcd * mpx + (idx % mpx)) * BM;
  int n0 = (idx / mpx) * BN;
  int NT = K / BK;
  int sr[4], sc[4];
#pragma unroll
  for (int i = 0; i < 4; i++) {
    int c = w * 4 + i;
    sr[i] = (c >> 1) * 16 + l15;
    sc[i] = (c & 1) * 32 + quad * 8;
  }
  f32x4 acc[4][4] = {};
  for (int t = 0; t < NT; t++) {
    __syncthreads();
    int k0 = t * BK;
#pragma unroll
    for (int i = 0; i < 4; i++) {
      int c = w * 4 + i;
      gload16(A + (size_t)(m0 + sr[i]) * lda + k0 + sc[i], As + c * 512);
      gload16(Bt + (size_t)(n0 + sr[i]) * K + k0 + sc[i], Bs + c * 512);
    }
    __syncthreads();
#pragma unroll
    for (int kk = 0; kk < 2; kk++) {
      bf16x8 af[4], bfv[4];
#pragma unroll
      for (int i = 0; i < 4; i++) {
        int ga = (w >> 1) * 4 + i;
        int gb = (w & 1) * 4 + i;
        af[i] = *(const bf16x8*)(As + (ga * 2 + kk) * 512 + lane * 8);
        bfv[i] = *(const bf16x8*)(Bs + (gb * 2 + kk) * 512 + lane * 8);
      }
#pragma unroll
      for (int mt = 0; mt < 4; mt++)
#pragma unroll
        for (int nt = 0; nt < 4; nt++)
          acc[mt][nt] = __builtin_amdgcn_mfma_f32_16x16x32_bf16(
              af[mt], bfv[nt], acc[mt][nt], 0, 0, 0);
    }
  }
#pragma unroll
  for (int nt = 0; nt < 4; nt++) {
    int col = n0 + wn + nt * 16 + l15;
    float bv = bias[col];
#pragma unroll
    for (int mt = 0; mt < 4; mt++) {
      int row = m0 + wm + mt * 16 + quad * 4;
#pragma unroll
      for (int r = 0; r < 4; r++) {
        float v = acc[mt][nt][r] + bv;
        size_t idx2 = (size_t)(row + r) * N + col;
        if (EPI == 4) {
          v += res[idx2];
          ((float*)Cv)[idx2] = v;
        } else {
          if (EPI == 2) v = 0.5f * v * (1.0f + erff(v * 0.70710678118654752f));
          ((u16*)Cv)[idx2] = f2bf(v);
        }
      }
    }
  }
}

// ---------------------------------------------------------------- GEMM 256x64, 512 threads
// R11: A-heavy tile with REAL TLP. BM=256, BN=64, 8 waves (4M x 2N wave
// grid, per-wave 64x32 out, acc 4x2 f32x4 ~= 90 VGPR total), BK=64,
// double-buffered = 80KB LDS -> 2 blocks/CU = 16 waves/CU (R9's failure
// was this geometry at 256 threads = 8 waves/CU, Occupancy 20%).
// Counted vmcnt(5): 5 gloads/thread/K-tile (A:4, B:1), stage(t+1) issued
// before compute(t), waited one FULL iteration later; never vmcnt(0)
// in-loop. Fragment-major 1KB subtiles (0 conflicts; m173 pre-permuted
// global source). Tile economics: 105 FLOP per L2-byte vs 65 for 128^2.
// EPI 1: fused-QKV routing — output col segment s=col/768 goes to
//   ((u16*)Cv) + s*16384*768 (qb|kb|vb contiguous), col%768 within.
//   Valid since each block's 64-col span lies in one segment (768%64==0).
template <int EPI>
__global__ __launch_bounds__(512, 4) void gemm512_bt(
    const u16* __restrict__ A, const u16* __restrict__ Bt,
    const float* __restrict__ bias, const float* __restrict__ res,
    void* __restrict__ Cv, int M, int N, int K, int lda) {
  __shared__ u16 As[2][256 * 64];   // 32 subtiles x 1KB each buffer
  __shared__ u16 Bs[2][64 * 64];    // 8 subtiles x 1KB
  int tid = threadIdx.x, lane = tid & 63, w = tid >> 6;   // w in 0..7
  int l15 = lane & 15, quad = lane >> 4;
  int wr = w >> 1, wc = w & 1;      // 4M x 2N wave grid
  int GX = gridDim.x;
  int f = blockIdx.y * GX + blockIdx.x;
  int mpx = GX >> 3;
  int xcd = f & 7, idx = f >> 3;
  int m0 = (xcd * mpx + (idx % mpx)) * 256;
  int n0 = (idx / mpx) * 64;
  int NT = K / 64;
  // staging: A chunk c=w*4+i (c 0..31): row (c>>1)*16+l15, col-half c&1;
  // B chunk c=w (0..7): row (c>>1)*16+l15, col-half c&1.
  // prologue: stage tile 0 into buf 0
#pragma unroll
  for (int i = 0; i < 4; i++) {
    int c = w * 4 + i;
    gload16(A + (size_t)(m0 + (c >> 1) * 16 + l15) * lda + (c & 1) * 32 + quad * 8,
            As[0] + c * 512);
  }
  gload16(Bt + (size_t)(n0 + (w >> 1) * 16 + l15) * K + (w & 1) * 32 + quad * 8,
          Bs[0] + w * 512);
  f32x4 acc[4][2] = {};
  for (int t = 0; t < NT; t++) {
    int cur = t & 1;
    // stage next tile into the other buffer (WAR on buf^1 is guarded by
    // the barrier that ended iteration t-1)
    int k0 = (t + 1 < NT) ? (t + 1) * 64 : 0;   // wraparound: harmless
#pragma unroll
    for (int i = 0; i < 4; i++) {
      int c = w * 4 + i;
      gload16(A + (size_t)(m0 + (c >> 1) * 16 + l15) * lda + k0 + (c & 1) * 32 + quad * 8,
              As[cur ^ 1] + c * 512);
    }
    gload16(Bt + (size_t)(n0 + (w >> 1) * 16 + l15) * K + k0 + (w & 1) * 32 + quad * 8,
            Bs[cur ^ 1] + w * 512);
    // wait ONLY the previous iteration's 5 loads (tile t); ours keep flying
    asm volatile("s_waitcnt vmcnt(5)" ::: "memory");
    __builtin_amdgcn_s_barrier();    // tile t visible to all waves
    const u16* ab = As[cur];
    const u16* bb = Bs[cur];
#pragma unroll
    for (int kk = 0; kk < 2; kk++) {
      bf16x8 af[4], bfv[2];
#pragma unroll
      for (int i = 0; i < 4; i++) {
        int rg = wr * 4 + i;          // A row-group 0..15
        af[i] = *(const bf16x8*)(ab + (rg * 2 + kk) * 512 + lane * 8);
      }
#pragma unroll
      for (int i = 0; i < 2; i++) {
        int rg = wc * 2 + i;          // B row-group 0..3
        bfv[i] = *(const bf16x8*)(bb + (rg * 2 + kk) * 512 + lane * 8);
      }
#pragma unroll
      for (int mt = 0; mt < 4; mt++)
#pragma unroll
        for (int nt = 0; nt < 2; nt++)
          acc[mt][nt] = __builtin_amdgcn_mfma_f32_16x16x32_bf16(
              af[mt], bfv[nt], acc[mt][nt], 0, 0, 0);
    }
    __builtin_amdgcn_s_barrier();    // compute(t) done before stage(t+2)
  }
  // drain dangling wraparound prefetch before LDS liveness ends
  asm volatile("s_waitcnt vmcnt(0)" ::: "memory");
  // epilogue: C/D layout col=lane&15, row=quad*4+reg
  int seg = (EPI == 1) ? (n0 >= 1536 ? 2 : (n0 >= 768 ? 1 : 0)) : 0;
#pragma unroll
  for (int nt = 0; nt < 2; nt++) {
    int col = n0 + wc * 32 + nt * 16 + l15;
    float bv = bias[col];
#pragma unroll
    for (int mt = 0; mt < 4; mt++) {
      int row = m0 + wr * 64 + mt * 16 + quad * 4;
#pragma unroll
      for (int r = 0; r < 4; r++) {
        float v = acc[mt][nt][r] + bv;
        if (EPI == 1) {
          u16* outp = (u16*)Cv + (size_t)seg * 16384 * 768;
          outp[(size_t)(row + r) * 768 + (col - seg * 768)] = f2bf(v);
        } else {
          size_t idx2 = (size_t)(row + r) * N + col;
          if (EPI == 4) {
            v += res[idx2];
            ((float*)Cv)[idx2] = v;
          } else {
            if (EPI == 2) v = 0.5f * v * (1.0f + erff(v * 0.70710678118654752f));
            ((u16*)Cv)[idx2] = f2bf(v);
          }
        }
      }
    }
  }
}

// ---------------------------------------------------------------- attention
// R6-proven compact version (154.6us): q,k: [16384,768] head-sliced;
// vt: [bh][96][1024]; o dense [16384,768]. Padded LDS strides; 2-phase
// schedule; double-buffered ks/vts; wraparound reg prefetch; ONE
// barrier/kt; XCD swizzle; per-lane partial li; scale folded into exp.
#define QSS 104
#define VSS 72
#define PSS 72
__global__ __launch_bounds__(256, 2) void attn_k(const u16* __restrict__ q,
                                                 const u16* __restrict__ k,
                                                 const u16* __restrict__ vt,
                                                 u16* __restrict__ o) {
  __shared__ u16 qs[64 * QSS];
  __shared__ u16 ks[2][64 * QSS];
  __shared__ u16 vts[2][96 * VSS];
  __shared__ u16 ps[4 * 16 * PSS];
  int tid = threadIdx.x, lane = tid & 63, w = tid >> 6;
  int l15 = lane & 15, quad = lane >> 4;
  int f = blockIdx.y * 16 + blockIdx.x;
  int xcd = f & 7, idx = f >> 3;
  int bh = xcd * 16 + (idx & 15);
  int qt = idx >> 4;
  int b = bh >> 3, h = bh & 7;
  const u16* qbase = q + (size_t)(b * 1024 + qt * 64) * 768 + h * 96;
  const u16* kbase = k + (size_t)(b * 1024) * 768 + h * 96;
  const u16* vtbase = vt + (size_t)bh * 96 * 1024;
  int kr[3], ko[3], vr[3], vo[3];
#pragma unroll
  for (int i = 0; i < 3; i++) {
    int c = tid + i * 256;
    kr[i] = c / 12; ko[i] = (c % 12) * 8;
    vr[i] = c >> 3; vo[i] = (c & 7) * 8;
  }
#pragma unroll
  for (int i = 0; i < 3; i++)
    *(uint4*)(qs + kr[i] * QSS + ko[i]) =
        *(const uint4*)(qbase + (size_t)kr[i] * 768 + ko[i]);
  uint4 kreg[3], vreg[3];
#pragma unroll
  for (int i = 0; i < 3; i++) {
    kreg[i] = *(const uint4*)(kbase + (size_t)kr[i] * 768 + ko[i]);
    vreg[i] = *(const uint4*)(vtbase + (size_t)vr[i] * 1024 + vo[i]);
  }
#pragma unroll
  for (int i = 0; i < 3; i++) {
    *(uint4*)(ks[0] + kr[i] * QSS + ko[i]) = kreg[i];
    *(uint4*)(vts[0] + vr[i] * VSS + vo[i]) = vreg[i];
  }
  __syncthreads();

  float mi[4], li[4];
#pragma unroll
  for (int r = 0; r < 4; r++) { mi[r] = -1e30f; li[r] = 0.f; }
  f32x4 oacc[6] = {};
  const float scale = 0.10206207261596577f; // 1/sqrt(96)
  for (int kt = 0; kt < 16; kt++) {
    int cur = kt & 1, nxt = cur ^ 1;
    int ktn = (kt + 1) & 15;
#pragma unroll
    for (int i = 0; i < 3; i++) {
      kreg[i] = *(const uint4*)(kbase + (size_t)(ktn * 64 + kr[i]) * 768 + ko[i]);
      vreg[i] = *(const uint4*)(vtbase + (size_t)vr[i] * 1024 + ktn * 64 + vo[i]);
    }
    f32x4 s[4] = {};
#pragma unroll
    for (int kk = 0; kk < 3; kk++) {
      bf16x8 a = *(const bf16x8*)(qs + (w * 16 + l15) * QSS + kk * 32 + quad * 8);
#pragma unroll
      for (int nt = 0; nt < 4; nt++) {
        bf16x8 bb =
            *(const bf16x8*)(ks[cur] + (nt * 16 + l15) * QSS + kk * 32 + quad * 8);
        s[nt] = __builtin_amdgcn_mfma_f32_16x16x32_bf16(a, bb, s[nt], 0, 0, 0);
      }
    }
#pragma unroll
    for (int r = 0; r < 4; r++) {
      float sv[4], mx = -1e30f;
#pragma unroll
      for (int nt = 0; nt < 4; nt++) {
        sv[nt] = s[nt][r];
        mx = fmaxf(mx, sv[nt]);
      }
#pragma unroll
      for (int off = 1; off < 16; off <<= 1) mx = fmaxf(mx, __shfl_xor(mx, off, 16));
      float mnew = fmaxf(mi[r], mx);
      float alpha = __expf((mi[r] - mnew) * scale);
      float rs = 0.f;
#pragma unroll
      for (int nt = 0; nt < 4; nt++) {
        sv[nt] = __expf((sv[nt] - mnew) * scale);
        rs += sv[nt];
      }
      li[r] = li[r] * alpha + rs;
      mi[r] = mnew;
#pragma unroll
      for (int ht = 0; ht < 6; ht++) oacc[ht][r] *= alpha;
      int prow = quad * 4 + r;
#pragma unroll
      for (int nt = 0; nt < 4; nt++)
        ps[w * 16 * PSS + prow * PSS + nt * 16 + l15] = f2bf(sv[nt]);
    }
    asm volatile("s_waitcnt lgkmcnt(0)" ::: "memory");
#pragma unroll
    for (int kk = 0; kk < 2; kk++) {
      bf16x8 a = *(const bf16x8*)(ps + w * 16 * PSS + l15 * PSS + kk * 32 + quad * 8);
#pragma unroll
      for (int ht = 0; ht < 6; ht++) {
        bf16x8 bb =
            *(const bf16x8*)(vts[cur] + (ht * 16 + l15) * VSS + kk * 32 + quad * 8);
        oacc[ht] = __builtin_amdgcn_mfma_f32_16x16x32_bf16(a, bb, oacc[ht], 0, 0, 0);
      }
    }
#pragma unroll
    for (int i = 0; i < 3; i++) {
      *(uint4*)(ks[nxt] + kr[i] * QSS + ko[i]) = kreg[i];
      *(uint4*)(vts[nxt] + vr[i] * VSS + vo[i]) = vreg[i];
    }
    __syncthreads();
  }
#pragma unroll
  for (int r = 0; r < 4; r++)
#pragma unroll
    for (int off = 1; off < 16; off <<= 1) li[r] += __shfl_xor(li[r], off, 16);
  u16* obase = o + (size_t)(b * 1024 + qt * 64 + w * 16) * 768 + h * 96;
#pragma unroll
  for (int r = 0; r < 4; r++) {
    float inv = 1.0f / li[r];
    int row = quad * 4 + r;
#pragma unroll
    for (int ht = 0; ht < 6; ht++)
      obase[(size_t)row * 768 + ht * 16 + l15] = f2bf(oacc[ht][r] * inv);
  }
}

// ---------------------------------------------------------------- launch
// d_out timeline: vtrans writes VT into d_out -> attn reads it -> Wo-GEMM
// overwrites d_out with y1 (VT dead) -> FFN2 reads res=y1, writes 1:1.
// ws: weights 14.2MB + bqkv + hb,qb,kb,vb 4x25.2MB ~= 115MB (proven).
// hb: h -> f-chunk(lo); qb: q -> f-chunk(hi); kb: k -> h2; vb: v -> attn_out.
// qb,kb,vb contiguous => fused-QKV EPI1 routing (seg stride 16384*768).
extern "C" void kernel_launch(void* const* d_in, const int* in_sizes, int n_in,
                              void* d_out, int out_size, void* d_ws,
                              size_t ws_size, hipStream_t stream) {
  const float* x = (const float*)d_in[0];
  const float* gamma = (const float*)d_in[1];
  const float* beta = (const float*)d_in[2];
  const float* Wq = (const float*)d_in[3];
  const float* bq = (const float*)d_in[4];
  const float* Wk = (const float*)d_in[5];
  const float* bk = (const float*)d_in[6];
  const float* Wv = (const float*)d_in[7];
  const float* bv = (const float*)d_in[8];
  const float* Wo = (const float*)d_in[9];
  const float* bo = (const float*)d_in[10];
  const float* W1 = (const float*)d_in[11];
  const float* b1 = (const float*)d_in[12];
  const float* W2 = (const float*)d_in[13];
  const float* b2 = (const float*)d_in[14];
  float* out = (float*)d_out;

  char* ws = (char*)d_ws;
  size_t off = 0;
  auto alloc = [&](size_t elems) {
    u16* p = (u16*)(ws + off);
    off += elems * sizeof(u16);
    return p;
  };
  u16* WqT = alloc(768 * 768);   // WqT|WkT|WvT adjacent = fused [2304,768]
  u16* WkT = alloc(768 * 768);
  u16* WvT = alloc(768 * 768);
  u16* WoT = alloc(768 * 768);
  u16* W1T = alloc((size_t)768 * 3072);    // [3072,768]
  u16* W2T = alloc((size_t)3072 * 768);    // [768,3072]
  float* bqkv = (float*)(ws + off); off += 2304 * sizeof(float);
  u16* hb = alloc((size_t)16384 * 768);    // h -> f-chunk(lo)
  u16* qb = alloc((size_t)16384 * 768);    // q -> f-chunk(hi)
  u16* kb = alloc((size_t)16384 * 768);    // k -> h2
  u16* vb = alloc((size_t)16384 * 768);    // v -> attn_out
  u16* vtb = (u16*)d_out;                  // VT lives in d_out until Wo

  // weight transposes fp32 -> bf16 [N,K]
  transpose4_k<<<dim3(24, 24, 4), 256, 0, stream>>>(Wq, Wk, Wv, Wo,
                                                    WqT, WkT, WvT, WoT);
  transpose_k<<<dim3(96, 24), 256, 0, stream>>>(W1, W1T, 768, 3072);
  transpose_k<<<dim3(24, 96), 256, 0, stream>>>(W2, W2T, 3072, 768);
  pack3_k<<<9, 256, 0, stream>>>(bq, bk, bv, bqkv);

  // LN1: x(fp32) -> h(bf16)
  ln_f32_k<<<16384, 256, 0, stream>>>(x, gamma, beta, hb);
  // fused QKV projection, routed to compact qb|kb|vb (EPI 1)
  gemm512_bt<1><<<dim3(64, 36), 512, 0, stream>>>(hb, WqT, bqkv, nullptr, qb,
                                                  16384, 2304, 768, 768);
  // V -> VT [bh][96][1024] into d_out
  vtrans_k<<<dim3(3, 32, 128), 256, 0, stream>>>(vb, vtb);
  // attention (compact q,k + VT) -> vb (v dead after vtrans)
  attn_k<<<dim3(16, 128), 256, 0, stream>>>(qb, kb, vtb, vb);
  // y1(fp32, in d_out) = attn_out @ Wo + bo + x  (overwrites VT - dead)
  gemm512_bt<4><<<dim3(64, 12), 512, 0, stream>>>(vb, WoT, bo, x, out,
                                                  16384, 768, 768, 768);
  // h2 = LN(y1) -> kb (k dead)
  ln_f32_k<<<16384, 256, 0, stream>>>(out, gamma, beta, kb);
  // FFN in 2 M-chunks of 8192 rows; f-chunk [8192,3072] bf16 (50.3MB)
  // lives in hb+qb (adjacent, both dead after attn)
  u16* fbuf = hb;
  for (int c = 0; c < 2; c++) {
    const u16* h2c = kb + (size_t)c * 8192 * 768;
    const float* y1c = out + (size_t)c * 8192 * 768;
    float* outc = out + (size_t)c * 8192 * 768;
    gemm512_bt<2><<<dim3(32, 48), 512, 0, stream>>>(h2c, W1T, b1, nullptr,
                                                    fbuf, 8192, 3072, 768, 768);
    gemm_bt<4><<<dim3(64, 6), 256, 0, stream>>>(fbuf, W2T, b2, y1c, outc,
                                                8192, 768, 3072, 3072);
  }
}

// Round 12
// 851.311 us; speedup vs baseline: 1.0939x; 1.0939x over previous
//
#include <hip/hip_runtime.h>

typedef unsigned short u16;
typedef float f32x4 __attribute__((ext_vector_type(4)));
typedef __bf16 bf16x8 __attribute__((ext_vector_type(8)));

#define AS1 __attribute__((address_space(1)))
#define AS3 __attribute__((address_space(3)))

__device__ __forceinline__ float bf2f(u16 h) {
  return __uint_as_float(((unsigned)h) << 16);
}
__device__ __forceinline__ u16 f2bf(float f) {
  unsigned u = __float_as_uint(f);
  unsigned r = (u + 0x7FFFu + ((u >> 16) & 1u)) >> 16;
  return (u16)r;
}
__device__ __forceinline__ void gload16(const u16* g, u16* l) {
  __builtin_amdgcn_global_load_lds((const AS1 void*)g, (AS3 void*)l, 16, 0, 0);
}

// ---------------------------------------------------------------- transpose
__global__ void transpose_k(const float* __restrict__ in, u16* __restrict__ out,
                            int R, int C) {
  __shared__ u16 t[32][33];
  int c0 = blockIdx.x * 32, r0 = blockIdx.y * 32;
  int tx = threadIdx.x & 31, ty = threadIdx.x >> 5; // 32 x 8
  for (int i = 0; i < 32; i += 8)
    t[ty + i][tx] = f2bf(in[(size_t)(r0 + ty + i) * C + c0 + tx]);
  __syncthreads();
  for (int i = 0; i < 32; i += 8)
    out[(size_t)(c0 + ty + i) * R + r0 + tx] = t[tx][ty + i];
}

__global__ void transpose4_k(const float* __restrict__ s0, const float* __restrict__ s1,
                             const float* __restrict__ s2, const float* __restrict__ s3,
                             u16* __restrict__ d0, u16* __restrict__ d1,
                             u16* __restrict__ d2, u16* __restrict__ d3) {
  __shared__ u16 t[32][33];
  const float* in = (blockIdx.z == 0) ? s0 : (blockIdx.z == 1) ? s1
                    : (blockIdx.z == 2) ? s2 : s3;
  u16* out = (blockIdx.z == 0) ? d0 : (blockIdx.z == 1) ? d1
             : (blockIdx.z == 2) ? d2 : d3;
  int c0 = blockIdx.x * 32, r0 = blockIdx.y * 32;
  int tx = threadIdx.x & 31, ty = threadIdx.x >> 5;
  for (int i = 0; i < 32; i += 8)
    t[ty + i][tx] = f2bf(in[(size_t)(r0 + ty + i) * 768 + c0 + tx]);
  __syncthreads();
  for (int i = 0; i < 32; i += 8)
    out[(size_t)(c0 + ty + i) * 768 + r0 + tx] = t[tx][ty + i];
}

__global__ void pack3_k(const float* __restrict__ a, const float* __restrict__ b,
                        const float* __restrict__ c, float* __restrict__ out) {
  int i = blockIdx.x * 256 + threadIdx.x;
  float v = (i < 768) ? a[i] : (i < 1536) ? b[i - 768] : c[i - 1536];
  out[i] = v;
}

// V(bf16) compact [16384,768] -> VT [bh][96][1024]
__global__ void vtrans_k(const u16* __restrict__ v, u16* __restrict__ vt) {
  __shared__ u16 t[32][33];
  int bh = blockIdx.z, b = bh >> 3, h = bh & 7;
  int n0 = blockIdx.y * 32, d0 = blockIdx.x * 32;
  int tx = threadIdx.x & 31, ty = threadIdx.x >> 5;
  const u16* src = v + (size_t)(b * 1024) * 768 + h * 96;
  for (int i = 0; i < 32; i += 8)
    t[ty + i][tx] = src[(size_t)(n0 + ty + i) * 768 + d0 + tx];
  __syncthreads();
  u16* dst = vt + ((size_t)bh * 96 + d0) * 1024 + n0;
  for (int i = 0; i < 32; i += 8)
    dst[(size_t)(ty + i) * 1024 + tx] = t[tx][ty + i];
}

// ---------------------------------------------------------------- layernorm
__global__ __launch_bounds__(256) void ln_f32_k(const float* __restrict__ x,
                                                const float* __restrict__ gamma,
                                                const float* __restrict__ beta,
                                                u16* __restrict__ out) {
  __shared__ float red[8];
  int row = blockIdx.x, t = threadIdx.x;
  const float* xr = x + (size_t)row * 768;
  float v[3], s = 0.f, s2 = 0.f;
#pragma unroll
  for (int i = 0; i < 3; i++) {
    v[i] = xr[t + i * 256];
    s += v[i]; s2 += v[i] * v[i];
  }
#pragma unroll
  for (int off = 1; off < 64; off <<= 1) {
    s += __shfl_xor(s, off, 64);
    s2 += __shfl_xor(s2, off, 64);
  }
  int w = t >> 6;
  if ((t & 63) == 0) { red[w] = s; red[4 + w] = s2; }
  __syncthreads();
  s = red[0] + red[1] + red[2] + red[3];
  s2 = red[4] + red[5] + red[6] + red[7];
  float mu = s * (1.f / 768.f);
  float var = s2 * (1.f / 768.f) - mu * mu;
  float rs = rsqrtf(var + 1e-5f);
  u16* orow = out + (size_t)row * 768;
#pragma unroll
  for (int i = 0; i < 3; i++) {
    int c = t + i * 256;
    orow[c] = f2bf((v[i] - mu) * rs * gamma[c] + beta[c]);
  }
}

// ---------------------------------------------------------------- GEMM 128x128
// R10-proven (used for Wo and FFN2): single 32KB buffer -> 5 blocks/CU;
// fragment-major 1KB subtiles (0 conflicts); XCD swizzle.
#define BM 128
#define BN 128
#define BK 64

template <int EPI>
__global__ __launch_bounds__(256, 4) void gemm_bt(
    const u16* __restrict__ A, const u16* __restrict__ Bt,
    const float* __restrict__ bias, const float* __restrict__ res,
    void* __restrict__ Cv, int M, int N, int K, int lda) {
  __shared__ u16 As[BM * BK];
  __shared__ u16 Bs[BN * BK];
  int tid = threadIdx.x, lane = tid & 63, w = tid >> 6;
  int l15 = lane & 15, quad = lane >> 4;
  int wm = (w >> 1) * 64, wn = (w & 1) * 64;
  int GX = gridDim.x;
  int f = blockIdx.y * GX + blockIdx.x;
  int mpx = GX >> 3;
  int xcd = f & 7, idx = f >> 3;
  int m0 = (xcd * mpx + (idx % mpx)) * BM;
  int n0 = (idx / mpx) * BN;
  int NT = K / BK;
  int sr[4], sc[4];
#pragma unroll
  for (int i = 0; i < 4; i++) {
    int c = w * 4 + i;
    sr[i] = (c >> 1) * 16 + l15;
    sc[i] = (c & 1) * 32 + quad * 8;
  }
  f32x4 acc[4][4] = {};
  for (int t = 0; t < NT; t++) {
    __syncthreads();
    int k0 = t * BK;
#pragma unroll
    for (int i = 0; i < 4; i++) {
      int c = w * 4 + i;
      gload16(A + (size_t)(m0 + sr[i]) * lda + k0 + sc[i], As + c * 512);
      gload16(Bt + (size_t)(n0 + sr[i]) * K + k0 + sc[i], Bs + c * 512);
    }
    __syncthreads();
#pragma unroll
    for (int kk = 0; kk < 2; kk++) {
      bf16x8 af[4], bfv[4];
#pragma unroll
      for (int i = 0; i < 4; i++) {
        int ga = (w >> 1) * 4 + i;
        int gb = (w & 1) * 4 + i;
        af[i] = *(const bf16x8*)(As + (ga * 2 + kk) * 512 + lane * 8);
        bfv[i] = *(const bf16x8*)(Bs + (gb * 2 + kk) * 512 + lane * 8);
      }
#pragma unroll
      for (int mt = 0; mt < 4; mt++)
#pragma unroll
        for (int nt = 0; nt < 4; nt++)
          acc[mt][nt] = __builtin_amdgcn_mfma_f32_16x16x32_bf16(
              af[mt], bfv[nt], acc[mt][nt], 0, 0, 0);
    }
  }
#pragma unroll
  for (int nt = 0; nt < 4; nt++) {
    int col = n0 + wn + nt * 16 + l15;
    float bv = bias[col];
#pragma unroll
    for (int mt = 0; mt < 4; mt++) {
      int row = m0 + wm + mt * 16 + quad * 4;
#pragma unroll
      for (int r = 0; r < 4; r++) {
        float v = acc[mt][nt][r] + bv;
        size_t idx2 = (size_t)(row + r) * N + col;
        if (EPI == 4) {
          v += res[idx2];
          ((float*)Cv)[idx2] = v;
        } else {
          if (EPI == 2) v = 0.5f * v * (1.0f + erff(v * 0.70710678118654752f));
          ((u16*)Cv)[idx2] = f2bf(v);
        }
      }
    }
  }
}

// ---------------------------------------------------------------- GEMM 256x256 8-phase
// R12: port of the 8-phase schedule (guide §5 template, T3+T4+T5).
// 512 thr / 8 waves (2M x 4N), per-wave out 128x64 (acc[8][4] f32x4).
// LDS 128KB = 2 bufs x {A 2 halves + B 2 halves, each 128x64 = 16KB of
// 16 fragment-major 1KB subtiles}. Wave wr reads only A-half wr; wave
// wc reads only B-half wc>>1 (both fixed per wave).
// Per K-tile (BK=64) 4 phases (pm,pn) = (0,0),(0,1),(1,0),(1,1):
//   {stage 1 half-tile (2 gload16) ; ds_read quadrant frags (A 8 reads
//    when pn==0, B 4 reads) ; [p3: vmcnt(4)] ; s_barrier ; setprio(1) ;
//    16 MFMA ; setprio(0) ; s_barrier}
// Stage schedule (slot freed -> restaged one phase later):
//   p0 -> (t+1,A1), p1 -> (t+1,B1), p2 -> (t+2,A0), p3 -> (t+2,B0)
// so vmcnt(4) at p3 leaves only (t+2,A0),(t+2,B0) in flight => tile t+1
// fully resident after p3's barrier. Never vmcnt(0) in-loop.
// Requires NT even (wraparound restage parity); NT = 768/64 = 12 here.
// EPI 1: fused-QKV routing seg = n0/768 (256 | 768 so block span is in
// one segment), out col = col - seg*768, seg stride 16384*768.
template <int EPI>
__global__ __launch_bounds__(512, 2) void gemm8p_bt(
    const u16* __restrict__ A, const u16* __restrict__ Bt,
    const float* __restrict__ bias, const float* __restrict__ res,
    void* __restrict__ Cv, int M, int N, int K, int lda) {
  __shared__ u16 lds_[2 * 32768];   // 128 KB
  int tid = threadIdx.x, lane = tid & 63, w = tid >> 6;   // w 0..7
  int l15 = lane & 15, quad = lane >> 4;
  int wr = w >> 2, wc = w & 3;      // 2M x 4N wave grid
  int GX = gridDim.x;
  int f = blockIdx.y * GX + blockIdx.x;
  int mpx = GX >> 3;
  int xcd = f & 7, idx = f >> 3;
  int m0 = (xcd * mpx + (idx % mpx)) * 256;
  int n0 = (idx / mpx) * 256;
  int NT = K / 64;

  // stage one half-tile: pos 0=A0,1=A1,2=B0,3=B1; wave w stages
  // subtiles w and w+8 (subtile s: rows (s>>1)*16+l15 local, k-half s&1)
  auto stage = [&](int st_tile, int pos) {
    int stt = st_tile >= NT ? st_tile - NT : st_tile;  // wrap (NT even)
    int kb = stt * 64;
    u16* dst = lds_ + (stt & 1) * 32768 + pos * 8192;
#pragma unroll
    for (int i = 0; i < 2; i++) {
      int s = w + i * 8;
      int rr = (s >> 1) * 16 + l15, cc = kb + (s & 1) * 32 + quad * 8;
      if (pos < 2)
        gload16(A + (size_t)(m0 + pos * 128 + rr) * lda + cc, dst + s * 512);
      else
        gload16(Bt + (size_t)(n0 + (pos - 2) * 128 + rr) * K + cc, dst + s * 512);
    }
  };

  f32x4 acc[8][4] = {};
  bf16x8 af[8], bf[4];

  // prologue: tile0 all 4 half-tiles + tile1 A0,B0; wait tile0, keep 4 fly
  stage(0, 0); stage(0, 1); stage(0, 2); stage(0, 3);
  stage(1, 0); stage(1, 2);
  asm volatile("s_waitcnt vmcnt(4)" ::: "memory");
  __builtin_amdgcn_s_barrier();

  for (int t = 0; t < NT; t++) {
    const u16* abase = lds_ + (t & 1) * 32768 + wr * 8192;
    const u16* bbase = lds_ + (t & 1) * 32768 + 16384 + (wc >> 1) * 8192;
#pragma unroll
    for (int p = 0; p < 4; p++) {
      const int pm = p >> 1, pn = p & 1;
      // stage per schedule
      if (p == 0) stage(t + 1, 1);
      else if (p == 1) stage(t + 1, 3);
      else if (p == 2) stage(t + 2, 0);
      else stage(t + 2, 2);
      // ds_read quadrant fragments (A persists across pn=0 -> pn=1)
      if (pn == 0) {
#pragma unroll
        for (int j = 0; j < 4; j++)
#pragma unroll
          for (int kk = 0; kk < 2; kk++)
            af[j * 2 + kk] = *(const bf16x8*)(
                abase + ((pm * 4 + j) * 2 + kk) * 512 + lane * 8);
      }
#pragma unroll
      for (int j = 0; j < 2; j++)
#pragma unroll
        for (int kk = 0; kk < 2; kk++)
          bf[j * 2 + kk] = *(const bf16x8*)(
              bbase + (((wc & 1) * 4 + pn * 2 + j) * 2 + kk) * 512 + lane * 8);
      if (p == 3) asm volatile("s_waitcnt vmcnt(4)" ::: "memory");
      __builtin_amdgcn_s_barrier();
      __builtin_amdgcn_s_setprio(1);
#pragma unroll
      for (int kk = 0; kk < 2; kk++)
#pragma unroll
        for (int j = 0; j < 4; j++)
#pragma unroll
          for (int n2 = 0; n2 < 2; n2++)
            acc[pm * 4 + j][pn * 2 + n2] = __builtin_amdgcn_mfma_f32_16x16x32_bf16(
                af[j * 2 + kk], bf[n2 * 2 + kk], acc[pm * 4 + j][pn * 2 + n2],
                0, 0, 0);
      __builtin_amdgcn_s_setprio(0);
      __builtin_amdgcn_s_barrier();
    }
  }
  asm volatile("s_waitcnt vmcnt(0)" ::: "memory");  // drain wrap prefetches

  // epilogue: C/D layout col=lane&15, row=quad*4+reg
  int seg = (EPI == 1) ? (n0 / 768) : 0;
#pragma unroll
  for (int ng = 0; ng < 4; ng++) {
    int col = n0 + wc * 64 + ng * 16 + l15;
    float bv = bias[col];
#pragma unroll
    for (int mg = 0; mg < 8; mg++) {
      int row = m0 + wr * 128 + mg * 16 + quad * 4;
#pragma unroll
      for (int r = 0; r < 4; r++) {
        float v = acc[mg][ng][r] + bv;
        if (EPI == 1) {
          u16* outp = (u16*)Cv + (size_t)seg * 16384 * 768;
          outp[(size_t)(row + r) * 768 + (col - seg * 768)] = f2bf(v);
        } else {
          size_t idx2 = (size_t)(row + r) * N + col;
          if (EPI == 2) v = 0.5f * v * (1.0f + erff(v * 0.70710678118654752f));
          ((u16*)Cv)[idx2] = f2bf(v);
        }
      }
    }
  }
}

// ---------------------------------------------------------------- attention
// R6-proven compact version: q,k [16384,768] head-sliced; vt [bh][96][1024];
// o dense. Padded LDS strides; 2-phase; double-buffered ks/vts; wraparound
// reg prefetch; ONE barrier/kt; XCD swizzle; per-lane partial li.
#define QSS 104
#define VSS 72
#define PSS 72
__global__ __launch_bounds__(256, 2) void attn_k(const u16* __restrict__ q,
                                                 const u16* __restrict__ k,
                                                 const u16* __restrict__ vt,
                                                 u16* __restrict__ o) {
  __shared__ u16 qs[64 * QSS];
  __shared__ u16 ks[2][64 * QSS];
  __shared__ u16 vts[2][96 * VSS];
  __shared__ u16 ps[4 * 16 * PSS];
  int tid = threadIdx.x, lane = tid & 63, w = tid >> 6;
  int l15 = lane & 15, quad = lane >> 4;
  int f = blockIdx.y * 16 + blockIdx.x;
  int xcd = f & 7, idx = f >> 3;
  int bh = xcd * 16 + (idx & 15);
  int qt = idx >> 4;
  int b = bh >> 3, h = bh & 7;
  const u16* qbase = q + (size_t)(b * 1024 + qt * 64) * 768 + h * 96;
  const u16* kbase = k + (size_t)(b * 1024) * 768 + h * 96;
  const u16* vtbase = vt + (size_t)bh * 96 * 1024;
  int kr[3], ko[3], vr[3], vo[3];
#pragma unroll
  for (int i = 0; i < 3; i++) {
    int c = tid + i * 256;
    kr[i] = c / 12; ko[i] = (c % 12) * 8;
    vr[i] = c >> 3; vo[i] = (c & 7) * 8;
  }
#pragma unroll
  for (int i = 0; i < 3; i++)
    *(uint4*)(qs + kr[i] * QSS + ko[i]) =
        *(const uint4*)(qbase + (size_t)kr[i] * 768 + ko[i]);
  uint4 kreg[3], vreg[3];
#pragma unroll
  for (int i = 0; i < 3; i++) {
    kreg[i] = *(const uint4*)(kbase + (size_t)kr[i] * 768 + ko[i]);
    vreg[i] = *(const uint4*)(vtbase + (size_t)vr[i] * 1024 + vo[i]);
  }
#pragma unroll
  for (int i = 0; i < 3; i++) {
    *(uint4*)(ks[0] + kr[i] * QSS + ko[i]) = kreg[i];
    *(uint4*)(vts[0] + vr[i] * VSS + vo[i]) = vreg[i];
  }
  __syncthreads();

  float mi[4], li[4];
#pragma unroll
  for (int r = 0; r < 4; r++) { mi[r] = -1e30f; li[r] = 0.f; }
  f32x4 oacc[6] = {};
  const float scale = 0.10206207261596577f; // 1/sqrt(96)
  for (int kt = 0; kt < 16; kt++) {
    int cur = kt & 1, nxt = cur ^ 1;
    int ktn = (kt + 1) & 15;
#pragma unroll
    for (int i = 0; i < 3; i++) {
      kreg[i] = *(const uint4*)(kbase + (size_t)(ktn * 64 + kr[i]) * 768 + ko[i]);
      vreg[i] = *(const uint4*)(vtbase + (size_t)vr[i] * 1024 + ktn * 64 + vo[i]);
    }
    f32x4 s[4] = {};
#pragma unroll
    for (int kk = 0; kk < 3; kk++) {
      bf16x8 a = *(const bf16x8*)(qs + (w * 16 + l15) * QSS + kk * 32 + quad * 8);
#pragma unroll
      for (int nt = 0; nt < 4; nt++) {
        bf16x8 bb =
            *(const bf16x8*)(ks[cur] + (nt * 16 + l15) * QSS + kk * 32 + quad * 8);
        s[nt] = __builtin_amdgcn_mfma_f32_16x16x32_bf16(a, bb, s[nt], 0, 0, 0);
      }
    }
#pragma unroll
    for (int r = 0; r < 4; r++) {
      float sv[4], mx = -1e30f;
#pragma unroll
      for (int nt = 0; nt < 4; nt++) {
        sv[nt] = s[nt][r];
        mx = fmaxf(mx, sv[nt]);
      }
#pragma unroll
      for (int off = 1; off < 16; off <<= 1) mx = fmaxf(mx, __shfl_xor(mx, off, 16));
      float mnew = fmaxf(mi[r], mx);
      float alpha = __expf((mi[r] - mnew) * scale);
      float rs = 0.f;
#pragma unroll
      for (int nt = 0; nt < 4; nt++) {
        sv[nt] = __expf((sv[nt] - mnew) * scale);
        rs += sv[nt];
      }
      li[r] = li[r] * alpha + rs;
      mi[r] = mnew;
#pragma unroll
      for (int ht = 0; ht < 6; ht++) oacc[ht][r] *= alpha;
      int prow = quad * 4 + r;
#pragma unroll
      for (int nt = 0; nt < 4; nt++)
        ps[w * 16 * PSS + prow * PSS + nt * 16 + l15] = f2bf(sv[nt]);
    }
    asm volatile("s_waitcnt lgkmcnt(0)" ::: "memory");
#pragma unroll
    for (int kk = 0; kk < 2; kk++) {
      bf16x8 a = *(const bf16x8*)(ps + w * 16 * PSS + l15 * PSS + kk * 32 + quad * 8);
#pragma unroll
      for (int ht = 0; ht < 6; ht++) {
        bf16x8 bb =
            *(const bf16x8*)(vts[cur] + (ht * 16 + l15) * VSS + kk * 32 + quad * 8);
        oacc[ht] = __builtin_amdgcn_mfma_f32_16x16x32_bf16(a, bb, oacc[ht], 0, 0, 0);
      }
    }
#pragma unroll
    for (int i = 0; i < 3; i++) {
      *(uint4*)(ks[nxt] + kr[i] * QSS + ko[i]) = kreg[i];
      *(uint4*)(vts[nxt] + vr[i] * VSS + vo[i]) = vreg[i];
    }
    __syncthreads();
  }
#pragma unroll
  for (int r = 0; r < 4; r++)
#pragma unroll
    for (int off = 1; off < 16; off <<= 1) li[r] += __shfl_xor(li[r], off, 16);
  u16* obase = o + (size_t)(b * 1024 + qt * 64 + w * 16) * 768 + h * 96;
#pragma unroll
  for (int r = 0; r < 4; r++) {
    float inv = 1.0f / li[r];
    int row = quad * 4 + r;
#pragma unroll
    for (int ht = 0; ht < 6; ht++)
      obase[(size_t)row * 768 + ht * 16 + l15] = f2bf(oacc[ht][r] * inv);
  }
}

// ---------------------------------------------------------------- launch
// d_out timeline: vtrans writes VT into d_out -> attn reads it -> Wo-GEMM
// overwrites d_out with y1 (VT dead) -> FFN2 reads res=y1, writes 1:1.
// ws: weights 14.2MB + bqkv + hb,qb,kb,vb 4x25.2MB ~= 115MB (proven).
// qb,kb,vb contiguous => fused-QKV EPI1 routing (seg stride 16384*768).
extern "C" void kernel_launch(void* const* d_in, const int* in_sizes, int n_in,
                              void* d_out, int out_size, void* d_ws,
                              size_t ws_size, hipStream_t stream) {
  const float* x = (const float*)d_in[0];
  const float* gamma = (const float*)d_in[1];
  const float* beta = (const float*)d_in[2];
  const float* Wq = (const float*)d_in[3];
  const float* bq = (const float*)d_in[4];
  const float* Wk = (const float*)d_in[5];
  const float* bk = (const float*)d_in[6];
  const float* Wv = (const float*)d_in[7];
  const float* bv = (const float*)d_in[8];
  const float* Wo = (const float*)d_in[9];
  const float* bo = (const float*)d_in[10];
  const float* W1 = (const float*)d_in[11];
  const float* b1 = (const float*)d_in[12];
  const float* W2 = (const float*)d_in[13];
  const float* b2 = (const float*)d_in[14];
  float* out = (float*)d_out;

  char* ws = (char*)d_ws;
  size_t off = 0;
  auto alloc = [&](size_t elems) {
    u16* p = (u16*)(ws + off);
    off += elems * sizeof(u16);
    return p;
  };
  u16* WqT = alloc(768 * 768);   // WqT|WkT|WvT adjacent = fused [2304,768]
  u16* WkT = alloc(768 * 768);
  u16* WvT = alloc(768 * 768);
  u16* WoT = alloc(768 * 768);
  u16* W1T = alloc((size_t)768 * 3072);    // [3072,768]
  u16* W2T = alloc((size_t)3072 * 768);    // [768,3072]
  float* bqkv = (float*)(ws + off); off += 2304 * sizeof(float);
  u16* hb = alloc((size_t)16384 * 768);    // h -> f-chunk(lo)
  u16* qb = alloc((size_t)16384 * 768);    // q -> f-chunk(hi)
  u16* kb = alloc((size_t)16384 * 768);    // k -> h2
  u16* vb = alloc((size_t)16384 * 768);    // v -> attn_out
  u16* vtb = (u16*)d_out;                  // VT lives in d_out until Wo

  transpose4_k<<<dim3(24, 24, 4), 256, 0, stream>>>(Wq, Wk, Wv, Wo,
                                                    WqT, WkT, WvT, WoT);
  transpose_k<<<dim3(96, 24), 256, 0, stream>>>(W1, W1T, 768, 3072);
  transpose_k<<<dim3(24, 96), 256, 0, stream>>>(W2, W2T, 3072, 768);
  pack3_k<<<9, 256, 0, stream>>>(bq, bk, bv, bqkv);

  // LN1: x(fp32) -> h(bf16)
  ln_f32_k<<<16384, 256, 0, stream>>>(x, gamma, beta, hb);
  // fused QKV projection (8-phase 256^2), routed to compact qb|kb|vb
  gemm8p_bt<1><<<dim3(64, 9), 512, 0, stream>>>(hb, WqT, bqkv, nullptr, qb,
                                                16384, 2304, 768, 768);
  // V -> VT into d_out
  vtrans_k<<<dim3(3, 32, 128), 256, 0, stream>>>(vb, vtb);
  // attention (compact q,k + VT) -> vb
  attn_k<<<dim3(16, 128), 256, 0, stream>>>(qb, kb, vtb, vb);
  // y1(fp32, in d_out) = attn_out @ Wo + bo + x  (overwrites VT - dead)
  gemm_bt<4><<<dim3(128, 6), 256, 0, stream>>>(vb, WoT, bo, x, out,
                                               16384, 768, 768, 768);
  // h2 = LN(y1) -> kb
  ln_f32_k<<<16384, 256, 0, stream>>>(out, gamma, beta, kb);
  // FFN in 2 M-chunks of 8192 rows; f-chunk [8192,3072] in hb+qb
  u16* fbuf = hb;
  for (int c = 0; c < 2; c++) {
    const u16* h2c = kb + (size_t)c * 8192 * 768;
    const float* y1c = out + (size_t)c * 8192 * 768;
    float* outc = out + (size_t)c * 8192 * 768;
    gemm8p_bt<2><<<dim3(32, 12), 512, 0, stream>>>(h2c, W1T, b1, nullptr,
                                                   fbuf, 8192, 3072, 768, 768);
    gemm_bt<4><<<dim3(64, 6), 256, 0, stream>>>(fbuf, W2T, b2, y1c, outc,
                                                8192, 768, 3072, 3072);
  }
}